// Round 1
// baseline (101.617 us; speedup 1.0000x reference)
//
#include <hip/hip_runtime.h>

typedef __bf16 bf16x8 __attribute__((ext_vector_type(8)));
typedef __bf16 bf16x4 __attribute__((ext_vector_type(4)));
typedef float f32x16 __attribute__((ext_vector_type(16)));

constexpr int kB = 2048, kF = 1024, kP = 64, kK = 64;
constexpr int B_TILE = 256, F_TILE = 4;

// out[b,f] = max_p dot(x[b,:], ww[f,p,:]) * scale[f] + bias[f]
// MFMA 32x32x16 bf16 with M=p (reduction axis -> per-lane reg max), N=b.
__global__ __launch_bounds__(256, 2)
void affine_max_mfma(const float* __restrict__ x, const float* __restrict__ ww,
                     const float* __restrict__ scale, const float* __restrict__ bias,
                     float* __restrict__ out) {
  // XOR-swizzled bf16 tiles (row stride 128B would be a 32-way bank conflict)
  __shared__ __align__(16) char s_ww[F_TILE * kP * kK * 2];  // 32 KB
  __shared__ __align__(16) char s_x[B_TILE * kK * 2];        // 32 KB

  const int tid = threadIdx.x;
  const int bgroup = blockIdx.x >> 8;   // 0..7   (consecutive blockIdx = same bgroup,
  const int fgroup = blockIdx.x & 255;  // 0..255  different fgroup -> XCD round-robin)
  const int b0 = bgroup * B_TILE;
  const int f0 = fgroup * F_TILE;

  // ---- stage ww tile: 4 f-slices, fp32 -> bf16, row-XOR swizzle ----
  {
    const float* src = ww + (size_t)f0 * (kP * kK);
#pragma unroll
    for (int it = 0; it < 16; ++it) {
      const int e = it * 1024 + tid * 4;                 // 4 contiguous elems
      const float4 v = *reinterpret_cast<const float4*>(src + e);
      const int off = (e << 1) ^ (((e >> 6) & 7) << 4);  // row = e>>6 (mod 8 same)
      bf16x4 h;
      h[0] = (__bf16)v.x; h[1] = (__bf16)v.y; h[2] = (__bf16)v.z; h[3] = (__bf16)v.w;
      *reinterpret_cast<bf16x4*>(s_ww + off) = h;
    }
  }
  // ---- stage x tile: 256 rows x 64 k ----
  {
    const float* src = x + (size_t)b0 * kK;
#pragma unroll
    for (int it = 0; it < 16; ++it) {
      const int e = it * 1024 + tid * 4;
      const float4 v = *reinterpret_cast<const float4*>(src + e);
      const int off = (e << 1) ^ (((e >> 6) & 7) << 4);
      bf16x4 h;
      h[0] = (__bf16)v.x; h[1] = (__bf16)v.y; h[2] = (__bf16)v.z; h[3] = (__bf16)v.w;
      *reinterpret_cast<bf16x4*>(s_x + off) = h;
    }
  }
  __syncthreads();

  const int wv = tid >> 6;   // wave 0..3 -> owns f = f0 + wv
  const int lane = tid & 63;
  const int l31 = lane & 31;
  const int half = lane >> 5;
  const int f = f0 + wv;
  const float scl = scale[f];
  const float bia = bias[f];

  // A-frags: ww[f][p=mt*32+l31][kb..kb+7], loaded once, reused over all b-tiles
  bf16x8 afr[2][4];
#pragma unroll
  for (int mt = 0; mt < 2; ++mt)
#pragma unroll
    for (int ks = 0; ks < 4; ++ks) {
      const int p = mt * 32 + l31;
      const int kb = ks * 16 + half * 8;
      const int off = ((wv * 4096 + p * 64 + kb) << 1) ^ ((p & 7) << 4);
      afr[mt][ks] = *reinterpret_cast<const bf16x8*>(s_ww + off);
    }

#pragma unroll
  for (int nt = 0; nt < 8; ++nt) {
    const int brow = nt * 32 + l31;
    bf16x8 bfr[4];
#pragma unroll
    for (int ks = 0; ks < 4; ++ks) {
      const int kb = ks * 16 + half * 8;
      const int off = ((brow * 64 + kb) << 1) ^ ((brow & 7) << 4);
      bfr[ks] = *reinterpret_cast<const bf16x8*>(s_x + off);
    }
    f32x16 acc0 = {}, acc1 = {};
#pragma unroll
    for (int ks = 0; ks < 4; ++ks) {
      acc0 = __builtin_amdgcn_mfma_f32_32x32x16_bf16(afr[0][ks], bfr[ks], acc0, 0, 0, 0);
      acc1 = __builtin_amdgcn_mfma_f32_32x32x16_bf16(afr[1][ks], bfr[ks], acc1, 0, 0, 0);
    }
    // max over p: 16 regs x 2 M-tiles per lane, then lane-half exchange.
    float v = -__builtin_inff();
#pragma unroll
    for (int i = 0; i < 16; ++i) v = fmaxf(v, fmaxf(acc0[i], acc1[i]));
    v = fmaxf(v, __shfl_xor(v, 32));
    if (lane < 32) out[(b0 + brow) * kF + f] = v * scl + bia;
  }
}

extern "C" void kernel_launch(void* const* d_in, const int* in_sizes, int n_in,
                              void* d_out, int out_size, void* d_ws, size_t ws_size,
                              hipStream_t stream) {
  const float* x = (const float*)d_in[0];
  const float* ww = (const float*)d_in[1];
  const float* scale = (const float*)d_in[2];
  const float* bias = (const float*)d_in[3];
  float* out = (float*)d_out;
  dim3 grid((kB / B_TILE) * (kF / F_TILE));  // 8 * 256 = 2048 blocks
  dim3 block(256);
  hipLaunchKernelGGL(affine_max_mfma, grid, block, 0, stream,
                     x, ww, scale, bias, out);
}

// Round 2
// 93.470 us; speedup vs baseline: 1.0872x; 1.0872x over previous
//
#include <hip/hip_runtime.h>

typedef __bf16 bf16x8 __attribute__((ext_vector_type(8)));
typedef __bf16 bf16x4 __attribute__((ext_vector_type(4)));
typedef float f32x16 __attribute__((ext_vector_type(16)));

constexpr int kB = 2048, kF = 1024, kP = 64, kK = 64;
constexpr int B_TILE = 256;   // b rows per block
constexpr int F_CHUNK = 16;   // f per block = 4 passes x 4 waves
constexpr int N_PASS = 4;

// out[b,f] = max_p dot(x[b,:], ww[f,p,:]) * scale[f] + bias[f]
// MFMA 32x32x16 bf16, M=p (reduction axis -> per-lane reg max), N=b.
// ww A-frags read direct from global (L2-resident via XCD-partitioned f-range),
// x staged once to LDS then held in regs across all 4 f-passes.
__global__ __launch_bounds__(256, 2)
void affine_max_mfma(const float* __restrict__ x, const float* __restrict__ ww,
                     const float* __restrict__ scale, const float* __restrict__ bias,
                     float* __restrict__ out) {
  // 32 KB: x tile (bf16, XOR-swizzled); after B-frag loads, reused as the
  // out-transpose buffer (256 rows x 20 f32 padded = 20 KB).
  __shared__ __align__(16) char s_buf[32 * 1024];

  const int tid = threadIdx.x;
  const int bx = blockIdx.x;
  // XCD-aware: xcd = bx&7 (round-robin). XCD i owns fchunks [8i,8i+8)
  // = 128 f = 2.1 MB of ww -> fits its 4 MB L2; re-read by 8 bgroups from L2.
  const int fchunk = (bx & 7) * 8 + ((bx >> 3) & 7);
  const int bgroup = bx >> 6;
  const int b0 = bgroup * B_TILE;
  const int f0 = fchunk * F_CHUNK;

  // ---- stage x tile: 256 rows x 64 k, fp32 -> bf16, row-XOR swizzle ----
  {
    const float* src = x + (size_t)b0 * kK;
#pragma unroll
    for (int it = 0; it < 16; ++it) {
      const int e = it * 1024 + tid * 4;                 // 4 contiguous elems
      const float4 v = *reinterpret_cast<const float4*>(src + e);
      const int off = (e << 1) ^ (((e >> 6) & 7) << 4);  // row = e>>6
      bf16x4 h;
      h[0] = (__bf16)v.x; h[1] = (__bf16)v.y; h[2] = (__bf16)v.z; h[3] = (__bf16)v.w;
      *reinterpret_cast<bf16x4*>(s_buf + off) = h;
    }
  }
  __syncthreads();

  const int wv = tid >> 6;
  const int lane = tid & 63;
  const int l31 = lane & 31;
  const int half = lane >> 5;

  // ---- load ALL x B-frags into regs (held across the 4 f-passes) ----
  // bfr[nt][ks] = x[b0 + nt*32 + l31][ks*16 + half*8 .. +7]  (128 VGPRs)
  bf16x8 bfr[8][4];
#pragma unroll
  for (int nt = 0; nt < 8; ++nt) {
    const int brow = nt * 32 + l31;
#pragma unroll
    for (int ks = 0; ks < 4; ++ks) {
      const int kb = ks * 16 + half * 8;
      const int off = ((brow * 64 + kb) << 1) ^ ((brow & 7) << 4);
      bfr[nt][ks] = *reinterpret_cast<const bf16x8*>(s_buf + off);
    }
  }
  __syncthreads();  // x LDS now dead -> reuse as out buffer

  float* s_out = reinterpret_cast<float*>(s_buf);  // [256][20] padded f32

#pragma unroll 1
  for (int pass = 0; pass < N_PASS; ++pass) {
    const int f = f0 + pass * 4 + wv;  // this wave's f
    // ---- A-frags direct from global (L2): ww[f][p=mt*32+l31][kb..kb+7] ----
    bf16x8 afr[2][4];
#pragma unroll
    for (int mt = 0; mt < 2; ++mt) {
      const int p = mt * 32 + l31;
      const float* rowp = ww + (size_t)f * (kP * kK) + p * kK;
#pragma unroll
      for (int ks = 0; ks < 4; ++ks) {
        const int kb = ks * 16 + half * 8;
        const float4 lo = *reinterpret_cast<const float4*>(rowp + kb);
        const float4 hi = *reinterpret_cast<const float4*>(rowp + kb + 4);
        bf16x8 h;
        h[0] = (__bf16)lo.x; h[1] = (__bf16)lo.y; h[2] = (__bf16)lo.z; h[3] = (__bf16)lo.w;
        h[4] = (__bf16)hi.x; h[5] = (__bf16)hi.y; h[6] = (__bf16)hi.z; h[7] = (__bf16)hi.w;
        afr[mt][ks] = h;
      }
    }

#pragma unroll
    for (int nt = 0; nt < 8; ++nt) {
      f32x16 acc0 = {}, acc1 = {};
#pragma unroll
      for (int ks = 0; ks < 4; ++ks) {
        acc0 = __builtin_amdgcn_mfma_f32_32x32x16_bf16(afr[0][ks], bfr[nt][ks], acc0, 0, 0, 0);
        acc1 = __builtin_amdgcn_mfma_f32_32x32x16_bf16(afr[1][ks], bfr[nt][ks], acc1, 0, 0, 0);
      }
      // max over p: 32 values per lane, log-depth tree (fmax chains fuse to v_max3)
      float a[16];
#pragma unroll
      for (int i = 0; i < 16; ++i) a[i] = fmaxf(acc0[i], acc1[i]);
#pragma unroll
      for (int s = 8; s >= 1; s >>= 1)
#pragma unroll
        for (int i = 0; i < s; ++i) a[i] = fmaxf(a[i], a[i + s]);
      float v = fmaxf(a[0], __shfl_xor(a[0], 32));
      if (lane < 32) s_out[(nt * 32 + l31) * 20 + pass * 4 + wv] = v;
    }
  }
  __syncthreads();

  // ---- epilogue: affine + coalesced store, 16 f per b-row as float4 ----
  {
    const int q = tid & 3;                       // f sub-chunk
    const float4 scl = *reinterpret_cast<const float4*>(scale + f0 + q * 4);
    const float4 bia = *reinterpret_cast<const float4*>(bias + f0 + q * 4);
#pragma unroll
    for (int it = 0; it < 4; ++it) {
      const int b = (tid >> 2) + it * 64;
      const float4 vv = *reinterpret_cast<const float4*>(s_out + b * 20 + q * 4);
      float4 r;
      r.x = vv.x * scl.x + bia.x;
      r.y = vv.y * scl.y + bia.y;
      r.z = vv.z * scl.z + bia.z;
      r.w = vv.w * scl.w + bia.w;
      *reinterpret_cast<float4*>(out + (size_t)(b0 + b) * kF + f0 + q * 4) = r;
    }
  }
}

extern "C" void kernel_launch(void* const* d_in, const int* in_sizes, int n_in,
                              void* d_out, int out_size, void* d_ws, size_t ws_size,
                              hipStream_t stream) {
  const float* x = (const float*)d_in[0];
  const float* ww = (const float*)d_in[1];
  const float* scale = (const float*)d_in[2];
  const float* bias = (const float*)d_in[3];
  float* out = (float*)d_out;
  dim3 grid((kB / B_TILE) * (kF / F_CHUNK));  // 8 * 64 = 512 blocks, all resident
  dim3 block(256);
  hipLaunchKernelGGL(affine_max_mfma, grid, block, 0, stream,
                     x, ww, scale, bias, out);
}

// Round 3
// 91.274 us; speedup vs baseline: 1.1133x; 1.0241x over previous
//
#include <hip/hip_runtime.h>

typedef __bf16 bf16x8 __attribute__((ext_vector_type(8)));
typedef float f32x16 __attribute__((ext_vector_type(16)));

constexpr int kB = 2048, kF = 1024, kP = 64, kK = 64;
constexpr size_t WWPK_BYTES = (size_t)kF * kP * kK * 2;  // 8 MB bf16, frag-ordered

// Fragment chunk order (16 B chunks, 8 bf16 each):
//  ww chunk = ((f*4+ks)*2+half)*64 + mt*32 + p31   <- ww[f][mt*32+p31][ks*16+half*8+j]
//  x  chunk = (bt*8 + ks*2+half)*32 + b31          <- x[bt*32+b31][ks*16+half*8+j]
// so a wave's frag load (lane -> half=lane>>5, l31=lane&31) is contiguous.

__global__ __launch_bounds__(256, 8)
void pack_kernel(const float* __restrict__ x, const float* __restrict__ ww,
                 __bf16* __restrict__ wwpk, __bf16* __restrict__ xpk) {
  const int bx = blockIdx.x, tid = threadIdx.x;
  if (bx < 2048) {  // ww: 2048*256 threads * 8 elems = 1024*64*64
    const int g = bx * 256 + tid;
    const float4 lo = *reinterpret_cast<const float4*>(ww + (size_t)g * 8);
    const float4 hi = *reinterpret_cast<const float4*>(ww + (size_t)g * 8 + 4);
    const int f = g >> 9, rem = g & 511;
    const int p = rem >> 3, k8 = rem & 7;
    const int ks = k8 >> 1, half = k8 & 1, mt = p >> 5, p31 = p & 31;
    const int chunk = ((f * 4 + ks) * 2 + half) * 64 + mt * 32 + p31;
    bf16x8 h;
    h[0] = (__bf16)lo.x; h[1] = (__bf16)lo.y; h[2] = (__bf16)lo.z; h[3] = (__bf16)lo.w;
    h[4] = (__bf16)hi.x; h[5] = (__bf16)hi.y; h[6] = (__bf16)hi.z; h[7] = (__bf16)hi.w;
    *reinterpret_cast<bf16x8*>(wwpk + (size_t)chunk * 8) = h;
  } else {  // x: 64*256 threads * 8 elems = 2048*64
    const int g = (bx - 2048) * 256 + tid;
    const float4 lo = *reinterpret_cast<const float4*>(x + (size_t)g * 8);
    const float4 hi = *reinterpret_cast<const float4*>(x + (size_t)g * 8 + 4);
    const int b = g >> 3, k8 = g & 7;
    const int bt = b >> 5, b31 = b & 31;
    const int chunk = (bt * 8 + k8) * 32 + b31;
    bf16x8 h;
    h[0] = (__bf16)lo.x; h[1] = (__bf16)lo.y; h[2] = (__bf16)lo.z; h[3] = (__bf16)lo.w;
    h[4] = (__bf16)hi.x; h[5] = (__bf16)hi.y; h[6] = (__bf16)hi.z; h[7] = (__bf16)hi.w;
    *reinterpret_cast<bf16x8*>(xpk + (size_t)chunk * 8) = h;
  }
}

// out[b,f] = max_p dot(x[b,:], ww[f,p,:]) * scale[f] + bias[f]
// MFMA 32x32x16 bf16, M=p (max-reduced in regs), N=b.
// Per block: 8 f (2/wave, A-frags stationary in 64 VGPR), 512 b streamed.
// No input LDS, no main-loop barriers; reg double-buffered B-frags.
__global__ __launch_bounds__(256, 2)
void affine_max_mfma(const __bf16* __restrict__ wwpk, const __bf16* __restrict__ xpk,
                     const float* __restrict__ scale, const float* __restrict__ bias,
                     float* __restrict__ out) {
  __shared__ float s_out[512 * 10];  // out transpose buf; stride 10 -> <=2-way banks

  const int tid = threadIdx.x, bx = blockIdx.x;
  // XCD i (bx&7) owns fchunks [16i,16i+16): 1 MB ww + 256 KB x resident in its L2.
  const int xcd = bx & 7, j = bx >> 3;
  const int fchunk = xcd * 16 + (j & 15);   // 0..127 -> 8 f each
  const int bgroup = j >> 4;                // 0..3   -> 512 b each
  const int f0 = fchunk * 8;
  const int b0 = bgroup * 512;

  const int wv = tid >> 6, lane = tid & 63, l31 = lane & 31, half = lane >> 5;

  // ---- stationary A-frags: afr[fi][mt][ks], 64 VGPR ----
  const char* wbase = reinterpret_cast<const char*>(wwpk) + half * 1024 + l31 * 16;
  bf16x8 afr[2][2][4];
#pragma unroll
  for (int fi = 0; fi < 2; ++fi) {
    const size_t fb = (size_t)(f0 + wv * 2 + fi) * 8192;
#pragma unroll
    for (int mt = 0; mt < 2; ++mt)
#pragma unroll
      for (int ks = 0; ks < 4; ++ks)
        afr[fi][mt][ks] =
            *reinterpret_cast<const bf16x8*>(wbase + fb + ks * 2048 + mt * 512);
  }

  const char* xbase = reinterpret_cast<const char*>(xpk) +
                      (size_t)(bgroup * 16) * 4096 + half * 512 + l31 * 16;
  auto loadB = [&](int t, bf16x8 (&dst)[4]) {
#pragma unroll
    for (int ks = 0; ks < 4; ++ks)
      dst[ks] = *reinterpret_cast<const bf16x8*>(xbase + t * 4096 + ks * 1024);
  };
  auto compute = [&](int t, bf16x8 (&bfr)[4]) {
    f32x16 acc[2][2] = {};
#pragma unroll
    for (int ks = 0; ks < 4; ++ks)
#pragma unroll
      for (int fi = 0; fi < 2; ++fi)
#pragma unroll
        for (int mt = 0; mt < 2; ++mt)
          acc[fi][mt] = __builtin_amdgcn_mfma_f32_32x32x16_bf16(
              afr[fi][mt][ks], bfr[ks], acc[fi][mt], 0, 0, 0);
#pragma unroll
    for (int fi = 0; fi < 2; ++fi) {
      float a[16];
#pragma unroll
      for (int i = 0; i < 16; ++i) a[i] = fmaxf(acc[fi][0][i], acc[fi][1][i]);
#pragma unroll
      for (int s = 8; s >= 1; s >>= 1)
#pragma unroll
        for (int i = 0; i < s; ++i) a[i] = fmaxf(a[i], a[i + s]);
      const float v = fmaxf(a[0], __shfl_xor(a[0], 32));
      if (lane < 32) s_out[(t * 32 + l31) * 10 + wv * 2 + fi] = v;
    }
  };

  // ---- main loop: 16 b-tiles, reg double-buffered, no barriers ----
  bf16x8 bA[4], bB[4];
  loadB(0, bA);
#pragma unroll 1
  for (int t = 0; t < 14; t += 2) {
    loadB(t + 1, bB);
    compute(t, bA);
    loadB(t + 2, bA);
    compute(t + 1, bB);
  }
  loadB(15, bB);
  compute(14, bA);
  compute(15, bB);

  __syncthreads();

  // ---- epilogue: affine + float4 stores ----
  const int c4 = (tid & 1) * 4;
  const float4 scl = *reinterpret_cast<const float4*>(scale + f0 + c4);
  const float4 bia = *reinterpret_cast<const float4*>(bias + f0 + c4);
#pragma unroll
  for (int i = 0; i < 4; ++i) {
    const int row = i * 128 + (tid >> 1);
    const float2 u0 = *reinterpret_cast<const float2*>(&s_out[row * 10 + c4]);
    const float2 u1 = *reinterpret_cast<const float2*>(&s_out[row * 10 + c4 + 2]);
    float4 r;
    r.x = u0.x * scl.x + bia.x;
    r.y = u0.y * scl.y + bia.y;
    r.z = u1.x * scl.z + bia.z;
    r.w = u1.y * scl.w + bia.w;
    *reinterpret_cast<float4*>(out + (size_t)(b0 + row) * kF + f0 + c4) = r;
  }
}

extern "C" void kernel_launch(void* const* d_in, const int* in_sizes, int n_in,
                              void* d_out, int out_size, void* d_ws, size_t ws_size,
                              hipStream_t stream) {
  const float* x = (const float*)d_in[0];
  const float* ww = (const float*)d_in[1];
  const float* scale = (const float*)d_in[2];
  const float* bias = (const float*)d_in[3];
  float* out = (float*)d_out;
  __bf16* wwpk = (__bf16*)d_ws;
  __bf16* xpk = (__bf16*)((char*)d_ws + WWPK_BYTES);

  hipLaunchKernelGGL(pack_kernel, dim3(2048 + 64), dim3(256), 0, stream,
                     x, ww, wwpk, xpk);
  hipLaunchKernelGGL(affine_max_mfma, dim3(512), dim3(256), 0, stream,
                     wwpk, xpk, scale, bias, out);
}